// Round 18
// baseline (125.683 us; speedup 1.0000x reference)
//
#include <hip/hip_runtime.h>

#define T_TOK 1024
#define NEXP 8
#define HID 1024
#define INTER 2048
#define SLOT_CAP 2176
#define NSLOT 2048
#define MAXTILES 24  // sum ceil(n_e/128) <= 23

#define BK 32
#define SPLITK 2
#define KCHUNK (INTER / SPLITK)  // 1024

typedef __bf16 bf16x8 __attribute__((ext_vector_type(8)));
typedef float f32x4 __attribute__((ext_vector_type(4)));

typedef const __attribute__((address_space(1))) void gv_t;
typedef __attribute__((address_space(3))) void lv_t;
static __device__ __forceinline__ void dma16(const void* g, void* l) {
  __builtin_amdgcn_global_load_lds((gv_t*)g, (lv_t*)l, 16, 0, 0);
}
#define VMW(N) asm volatile("s_waitcnt vmcnt(" #N ")" ::: "memory")
#define LKW() asm volatile("s_waitcnt lgkmcnt(0)" ::: "memory")

// ---- workspace layout (bytes) ----
#define WS_COUNTS 0
#define WS_OFFSETS 64
#define WS_TEXPERT 128
#define WS_TGATE (WS_TEXPERT + T_TOK * 2 * 4)
#define WS_TRANK (WS_TGATE + T_TOK * 2 * 4)
#define WS_TOKEN_OF (WS_TRANK + T_TOK * 2 * 4)
#define WS_GATE_OF (WS_TOKEN_OF + SLOT_CAP * 4)
#define WS_SLOT_OF (WS_GATE_OF + SLOT_CAP * 4)
#define WS_TILE_E (WS_SLOT_OF + T_TOK * 2 * 4)
#define WS_TILE_R (WS_TILE_E + 256)
#define WS_NTILES (WS_TILE_R + 256)
#define WS_ABUF 65536
#define WS_YS (WS_ABUF + SLOT_CAP * INTER * 2)
// xg aliases YS (consumed by gemm1 before gemm2 writes ys)

// ---------------- router ----------------
__global__ void moe_router(const float* __restrict__ logits, int* __restrict__ counts,
                           int* __restrict__ t_expert, float* __restrict__ t_gate,
                           int* __restrict__ t_rank) {
  int t = blockIdx.x * blockDim.x + threadIdx.x;
  if (t >= T_TOK) return;
  float l[NEXP];
  float mx = -1e30f;
#pragma unroll
  for (int e = 0; e < NEXP; ++e) {
    l[e] = logits[t * NEXP + e];
    mx = fmaxf(mx, l[e]);
  }
  float s = 0.f;
#pragma unroll
  for (int e = 0; e < NEXP; ++e) {
    l[e] = __expf(l[e] - mx);
    s += l[e];
  }
  float inv = 1.f / s;
  int i0 = 0;
#pragma unroll
  for (int e = 1; e < NEXP; ++e)
    if (l[e] > l[i0]) i0 = e;
  int i1 = (i0 == 0) ? 1 : 0;
#pragma unroll
  for (int e = 0; e < NEXP; ++e)
    if (e != i0 && e != i1 && l[e] > l[i1]) i1 = e;
  int es[2] = {i0, i1};
#pragma unroll
  for (int k = 0; k < 2; ++k) {
    int e = es[k];
    int r = atomicAdd(&counts[e], 1);
    int p = t * 2 + k;
    t_expert[p] = e;
    t_gate[p] = l[e] * inv;
    t_rank[p] = r;
  }
}

// ---------------- assign ----------------
__global__ void moe_assign(const int* __restrict__ counts, int* __restrict__ offsets,
                           const int* __restrict__ t_expert, const float* __restrict__ t_gate,
                           const int* __restrict__ t_rank, int* __restrict__ token_of,
                           float* __restrict__ gate_of, int* __restrict__ slot_of,
                           int* __restrict__ tile_e, int* __restrict__ tile_r,
                           int* __restrict__ n_tiles) {
  __shared__ int off_s[NEXP];
  if (threadIdx.x == 0) {
    int s = 0, nt = 0;
    for (int e = 0; e < NEXP; ++e) {
      off_s[e] = s;
      offsets[e] = s;
      int ntile = (counts[e] + 127) >> 7;
      for (int r = 0; r < ntile; ++r) {
        tile_e[nt] = e;
        tile_r[nt] = r;
        ++nt;
      }
      s += counts[e];
    }
    *n_tiles = nt;
  }
  __syncthreads();
  for (int p = threadIdx.x; p < T_TOK * 2; p += blockDim.x) {
    int e = t_expert[p];
    int slot = off_s[e] + t_rank[p];
    token_of[slot] = p >> 1;
    gate_of[slot] = t_gate[p];
    slot_of[p] = slot;
  }
}

// ---------------- xgather ----------------
__global__ void moe_xgather(const float* __restrict__ x, const int* __restrict__ token_of,
                            __bf16* __restrict__ xg) {
  int idx = blockIdx.x * blockDim.x + threadIdx.x;
  int slot = idx >> 7;
  int c = (idx & 127) * 8;
  const float* src = x + (size_t)token_of[slot] * HID + c;
  float4 v0 = *(const float4*)src;
  float4 v1 = *(const float4*)(src + 4);
  bf16x8 o = {(__bf16)v0.x, (__bf16)v0.y, (__bf16)v0.z, (__bf16)v0.w,
              (__bf16)v1.x, (__bf16)v1.y, (__bf16)v1.z, (__bf16)v1.w};
  *(bf16x8*)&xg[(size_t)slot * HID + c] = o;
}

// ======================= GEMM1 =======================
// 256 threads, 4 waves (2M x 2N), BM=128, BN=64, wave tile 64x32.
// 3-stage DMA ring (72KB): stage = {A bf16 8KB; B1 fp32 8KB; B3 fp32 8KB}.
// Steady state: 12 DMAs/wave in flight across barriers (stages t+2, t+3);
// VMW(12) after refill guarantees stage t+1 complete. Cover ~2.5 iters.
__global__ __launch_bounds__(256, 2) void moe_gemm1(
    const __bf16* __restrict__ xg, const float* __restrict__ w1, const float* __restrict__ w3,
    const int* __restrict__ offsets, const int* __restrict__ counts,
    const int* __restrict__ tile_e, const int* __restrict__ tile_r,
    const int* __restrict__ n_tiles, __bf16* __restrict__ abuf) {
  if ((int)blockIdx.y >= *n_tiles) return;
  const int e = tile_e[blockIdx.y];
  const int rt = tile_r[blockIdx.y];
  const int n_e = counts[e];
  const int off_e = offsets[e];
  const int col0 = blockIdx.x * 64;
  const int tid = threadIdx.x;
  const int lane = tid & 63;
  const int w = tid >> 6;
  const int wr = (w >> 1) * 64;
  const int wc = (w & 1) * 32;
  const int lr = lane & 15, lg = lane >> 4;

  __shared__ __align__(16) unsigned char sm[3 * 24576];

  f32x4 acc_h[4][2], acc_u[4][2];
#pragma unroll
  for (int m = 0; m < 4; ++m)
#pragma unroll
    for (int n = 0; n < 2; ++n) {
      acc_h[m][n] = (f32x4){0.f, 0.f, 0.f, 0.f};
      acc_u[m][n] = (f32x4){0.f, 0.f, 0.f, 0.f};
    }

  // A DMA sources: chunks c = w*2+j; lane l -> row c*16+(l&15), 16B seg l>>4
  const int c0 = w * 2;
  const __bf16* aSrc[2];
#pragma unroll
  for (int j = 0; j < 2; ++j) {
    int row = (c0 + j) * 16 + (lane & 15);
    int r_loc = rt * 128 + row;
    int slot = off_e + (r_loc < n_e ? r_loc : n_e - 1);
    aSrc[j] = xg + (size_t)slot * HID + (lane >> 4) * 8;
  }
  // B DMA sources: chunk c = w*2+j; kr = c*4+(l>>4); cg_src = (l&15) ^ (w<<1)
  const float* b1Src[2];
  const float* b3Src[2];
#pragma unroll
  for (int j = 0; j < 2; ++j) {
    int kr = (c0 + j) * 4 + (lane >> 4);
    int cgs = (lane & 15) ^ (w << 1);
    size_t rowoff = (size_t)kr * INTER + col0 + cgs * 4;
    b1Src[j] = w1 + (size_t)e * HID * INTER + rowoff;
    b3Src[j] = w3 + (size_t)e * HID * INTER + rowoff;
  }

#define G1_ISSUE(S, K0)                                                        \
  {                                                                            \
    unsigned char* ibase = sm + (S)*24576;                                     \
    dma16(aSrc[0] + (K0), ibase + (c0 + 0) * 1024);                            \
    dma16(aSrc[1] + (K0), ibase + (c0 + 1) * 1024);                            \
    dma16(b1Src[0] + (size_t)(K0)*INTER, ibase + 8192 + (c0 + 0) * 1024);      \
    dma16(b1Src[1] + (size_t)(K0)*INTER, ibase + 8192 + (c0 + 1) * 1024);      \
    dma16(b3Src[0] + (size_t)(K0)*INTER, ibase + 16384 + (c0 + 0) * 1024);     \
    dma16(b3Src[1] + (size_t)(K0)*INTER, ibase + 16384 + (c0 + 1) * 1024);     \
  }

#define G1_BFRAG(dstf, matoff, N)                                              \
  bf16x8 dstf;                                                                 \
  {                                                                            \
    int col = wc + (N)*16 + lr;                                                \
    int g = (col >> 2) ^ (lg << 1);                                            \
    const unsigned char* bb =                                                  \
        base + (matoff) + lg * 2048 + g * 16 + (col & 3) * 4;                  \
    float v0 = *(const float*)(bb + 0 * 256), v1 = *(const float*)(bb + 1 * 256); \
    float v2 = *(const float*)(bb + 2 * 256), v3 = *(const float*)(bb + 3 * 256); \
    float v4 = *(const float*)(bb + 4 * 256), v5 = *(const float*)(bb + 5 * 256); \
    float v6 = *(const float*)(bb + 6 * 256), v7 = *(const float*)(bb + 7 * 256); \
    dstf = (bf16x8){(__bf16)v0, (__bf16)v1, (__bf16)v2, (__bf16)v3,            \
                    (__bf16)v4, (__bf16)v5, (__bf16)v6, (__bf16)v7};           \
  }

  const int NT = HID / BK;  // 32
  G1_ISSUE(0, 0);
  G1_ISSUE(1, BK);
  G1_ISSUE(2, 2 * BK);
  VMW(12);  // stage 0 ready; stages 1,2 in flight
  __builtin_amdgcn_s_barrier();

  int s = 0;
#pragma unroll 1
  for (int t = 0; t < NT; ++t) {
    const unsigned char* base = sm + s * 24576;
    bf16x8 af[4];
#pragma unroll
    for (int m = 0; m < 4; ++m)
      af[m] = *(const bf16x8*)(base + (wr + m * 16) * 64 + lg * 256 + lr * 16);
    G1_BFRAG(bf1a, 8192, 0);
    G1_BFRAG(bf1b, 8192, 1);
    G1_BFRAG(bf3a, 16384, 0);
    G1_BFRAG(bf3b, 16384, 1);
#pragma unroll
    for (int m = 0; m < 4; ++m) {
      acc_h[m][0] = __builtin_amdgcn_mfma_f32_16x16x32_bf16(af[m], bf1a, acc_h[m][0], 0, 0, 0);
      acc_h[m][1] = __builtin_amdgcn_mfma_f32_16x16x32_bf16(af[m], bf1b, acc_h[m][1], 0, 0, 0);
      acc_u[m][0] = __builtin_amdgcn_mfma_f32_16x16x32_bf16(af[m], bf3a, acc_u[m][0], 0, 0, 0);
      acc_u[m][1] = __builtin_amdgcn_mfma_f32_16x16x32_bf16(af[m], bf3b, acc_u[m][1], 0, 0, 0);
    }
    LKW();
    __builtin_amdgcn_s_barrier();  // all waves done reading stage s
    if (t + 3 < NT) {
      G1_ISSUE(s, (t + 3) * BK);  // refill just-consumed stage
      VMW(12);                    // stage t+1 done; t+2, t+3 in flight
    } else if (t + 2 < NT) {
      VMW(6);                     // stage t+1 done; t+2 in flight
    } else {
      VMW(0);
    }
    __builtin_amdgcn_s_barrier();
    s = (s == 2) ? 0 : s + 1;
  }
#undef G1_ISSUE
#undef G1_BFRAG

  // epilogue: a = silu(h) * u, store bf16
#pragma unroll
  for (int m = 0; m < 4; ++m)
#pragma unroll
    for (int n = 0; n < 2; ++n) {
      int col = col0 + wc + n * 16 + lr;
#pragma unroll
      for (int r = 0; r < 4; ++r) {
        int row_loc = rt * 128 + wr + m * 16 + lg * 4 + r;
        if (row_loc < n_e) {
          float h = acc_h[m][n][r];
          float u = acc_u[m][n][r];
          float a = h / (1.f + __expf(-h)) * u;
          abuf[(size_t)(off_e + row_loc) * INTER + col] = (__bf16)a;
        }
      }
    }
}

// ======================= GEMM2 =======================
// 256 threads, 4 waves, BM=128, BN=64, split-K=2; 3-stage ring (48KB).
// Steady state: 8 DMAs/wave in flight; VMW(8) after refill.
__global__ __launch_bounds__(256, 3) void moe_gemm2(
    const __bf16* __restrict__ abuf, const float* __restrict__ w2,
    const int* __restrict__ offsets, const int* __restrict__ counts,
    const float* __restrict__ gate_of, const int* __restrict__ tile_e,
    const int* __restrict__ tile_r, const int* __restrict__ n_tiles,
    float* __restrict__ yslot) {
  if ((int)blockIdx.y >= *n_tiles) return;
  const int e = tile_e[blockIdx.y];
  const int rt = tile_r[blockIdx.y];
  const int sk = blockIdx.z;
  const int n_e = counts[e];
  const int off_e = offsets[e];
  const int col0 = blockIdx.x * 64;
  const int kbase = sk * KCHUNK;
  const int tid = threadIdx.x;
  const int lane = tid & 63;
  const int w = tid >> 6;
  const int wr = (w >> 1) * 64;
  const int wc = (w & 1) * 32;
  const int lr = lane & 15, lg = lane >> 4;

  __shared__ __align__(16) unsigned char sm[3 * 16384];

  f32x4 acc[4][2];
#pragma unroll
  for (int m = 0; m < 4; ++m)
#pragma unroll
    for (int n = 0; n < 2; ++n) acc[m][n] = (f32x4){0.f, 0.f, 0.f, 0.f};

  const int c0 = w * 2;
  const __bf16* aSrc[2];
#pragma unroll
  for (int j = 0; j < 2; ++j) {
    int row = (c0 + j) * 16 + (lane & 15);
    int r_loc = rt * 128 + row;
    int slot = off_e + (r_loc < n_e ? r_loc : n_e - 1);
    aSrc[j] = abuf + (size_t)slot * INTER + kbase + (lane >> 4) * 8;
  }
  const float* bSrc[2];
#pragma unroll
  for (int j = 0; j < 2; ++j) {
    int kr = (c0 + j) * 4 + (lane >> 4);
    int cgs = (lane & 15) ^ (w << 1);
    bSrc[j] = w2 + (size_t)e * INTER * HID + (size_t)(kbase + kr) * HID + col0 + cgs * 4;
  }

#define G2_ISSUE(S, K0)                                                        \
  {                                                                            \
    unsigned char* ibase = sm + (S)*16384;                                     \
    dma16(aSrc[0] + (K0), ibase + (c0 + 0) * 1024);                            \
    dma16(aSrc[1] + (K0), ibase + (c0 + 1) * 1024);                            \
    dma16(bSrc[0] + (size_t)(K0)*HID, ibase + 8192 + (c0 + 0) * 1024);         \
    dma16(bSrc[1] + (size_t)(K0)*HID, ibase + 8192 + (c0 + 1) * 1024);         \
  }
#define G2_BFRAG(dstf, N)                                                      \
  bf16x8 dstf;                                                                 \
  {                                                                            \
    int col = wc + (N)*16 + lr;                                                \
    int g = (col >> 2) ^ (lg << 1);                                            \
    const unsigned char* bb = base + 8192 + lg * 2048 + g * 16 + (col & 3) * 4; \
    float v0 = *(const float*)(bb + 0 * 256), v1 = *(const float*)(bb + 1 * 256); \
    float v2 = *(const float*)(bb + 2 * 256), v3 = *(const float*)(bb + 3 * 256); \
    float v4 = *(const float*)(bb + 4 * 256), v5 = *(const float*)(bb + 5 * 256); \
    float v6 = *(const float*)(bb + 6 * 256), v7 = *(const float*)(bb + 7 * 256); \
    dstf = (bf16x8){(__bf16)v0, (__bf16)v1, (__bf16)v2, (__bf16)v3,            \
                    (__bf16)v4, (__bf16)v5, (__bf16)v6, (__bf16)v7};           \
  }

  const int NT = KCHUNK / BK;  // 32
  G2_ISSUE(0, 0);
  G2_ISSUE(1, BK);
  G2_ISSUE(2, 2 * BK);
  VMW(8);
  __builtin_amdgcn_s_barrier();

  int s = 0;
#pragma unroll 1
  for (int t = 0; t < NT; ++t) {
    const unsigned char* base = sm + s * 16384;
    bf16x8 af[4];
#pragma unroll
    for (int m = 0; m < 4; ++m)
      af[m] = *(const bf16x8*)(base + (wr + m * 16) * 64 + lg * 256 + lr * 16);
    G2_BFRAG(bfa, 0);
    G2_BFRAG(bfb, 1);
#pragma unroll
    for (int m = 0; m < 4; ++m) {
      acc[m][0] = __builtin_amdgcn_mfma_f32_16x16x32_bf16(af[m], bfa, acc[m][0], 0, 0, 0);
      acc[m][1] = __builtin_amdgcn_mfma_f32_16x16x32_bf16(af[m], bfb, acc[m][1], 0, 0, 0);
    }
    LKW();
    __builtin_amdgcn_s_barrier();
    if (t + 3 < NT) {
      G2_ISSUE(s, (t + 3) * BK);
      VMW(8);
    } else if (t + 2 < NT) {
      VMW(4);
    } else {
      VMW(0);
    }
    __builtin_amdgcn_s_barrier();
    s = (s == 2) ? 0 : s + 1;
  }
#undef G2_ISSUE
#undef G2_BFRAG

  float* ysk = yslot + (size_t)sk * NSLOT * HID;
#pragma unroll
  for (int m = 0; m < 4; ++m)
#pragma unroll
    for (int n = 0; n < 2; ++n) {
      int col = col0 + wc + n * 16 + lr;
#pragma unroll
      for (int r = 0; r < 4; ++r) {
        int row_loc = rt * 128 + wr + m * 16 + lg * 4 + r;
        if (row_loc < n_e) {
          int slot = off_e + row_loc;
          ysk[(size_t)slot * HID + col] = gate_of[slot] * acc[m][n][r];
        }
      }
    }
}

// ---------------- combine ----------------
__global__ void moe_combine(const float* __restrict__ yslot, const int* __restrict__ slot_of,
                            float* __restrict__ out) {
  int i = blockIdx.x * blockDim.x + threadIdx.x;
  const int N4 = T_TOK * HID / 4;
  if (i >= N4) return;
  int t = i >> 8;
  int c4 = i & 255;
  int sA = slot_of[2 * t];
  int sB = slot_of[2 * t + 1];
  const float4* ys0 = (const float4*)yslot;
  const float4* ys1 = (const float4*)(yslot + (size_t)NSLOT * HID);
  float4 a = ys0[(size_t)sA * 256 + c4];
  float4 b = ys0[(size_t)sB * 256 + c4];
  float4 c = ys1[(size_t)sA * 256 + c4];
  float4 d = ys1[(size_t)sB * 256 + c4];
  float4 s;
  s.x = ((a.x + b.x) + c.x) + d.x;
  s.y = ((a.y + b.y) + c.y) + d.y;
  s.z = ((a.z + b.z) + c.z) + d.z;
  s.w = ((a.w + b.w) + c.w) + d.w;
  ((float4*)out)[i] = s;
}

// ---------------- launch ----------------
extern "C" void kernel_launch(void* const* d_in, const int* in_sizes, int n_in,
                              void* d_out, int out_size, void* d_ws, size_t ws_size,
                              hipStream_t stream) {
  const float* x = (const float*)d_in[0];
  const float* logits = (const float*)d_in[1];
  const float* w1 = (const float*)d_in[2];
  const float* w3 = (const float*)d_in[3];
  const float* w2 = (const float*)d_in[4];
  float* out = (float*)d_out;
  char* ws = (char*)d_ws;

  int* counts = (int*)(ws + WS_COUNTS);
  int* offsets = (int*)(ws + WS_OFFSETS);
  int* t_expert = (int*)(ws + WS_TEXPERT);
  float* t_gate = (float*)(ws + WS_TGATE);
  int* t_rank = (int*)(ws + WS_TRANK);
  int* token_of = (int*)(ws + WS_TOKEN_OF);
  float* gate_of = (float*)(ws + WS_GATE_OF);
  int* slot_of = (int*)(ws + WS_SLOT_OF);
  int* tile_e = (int*)(ws + WS_TILE_E);
  int* tile_r = (int*)(ws + WS_TILE_R);
  int* n_tiles = (int*)(ws + WS_NTILES);
  __bf16* abuf = (__bf16*)(ws + WS_ABUF);
  float* yslot = (float*)(ws + WS_YS);
  __bf16* xg = (__bf16*)(ws + WS_YS);

  hipMemsetAsync(counts, 0, 64, stream);
  moe_router<<<dim3(4), dim3(256), 0, stream>>>(logits, counts, t_expert, t_gate, t_rank);
  moe_assign<<<dim3(1), dim3(256), 0, stream>>>(counts, offsets, t_expert, t_gate, t_rank,
                                                token_of, gate_of, slot_of, tile_e, tile_r,
                                                n_tiles);
  moe_xgather<<<dim3(NSLOT * (HID / 8) / 256), dim3(256), 0, stream>>>(x, token_of, xg);
  moe_gemm1<<<dim3(INTER / 64, MAXTILES), dim3(256), 0, stream>>>(
      xg, w1, w3, offsets, counts, tile_e, tile_r, n_tiles, abuf);
  moe_gemm2<<<dim3(HID / 64, MAXTILES, SPLITK), dim3(256), 0, stream>>>(
      abuf, w2, offsets, counts, gate_of, tile_e, tile_r, n_tiles, yslot);
  moe_combine<<<dim3((T_TOK * HID / 4 + 255) / 256), dim3(256), 0, stream>>>(yslot, slot_of,
                                                                             out);
}

// Round 19
// 110.821 us; speedup vs baseline: 1.1341x; 1.1341x over previous
//
#include <hip/hip_runtime.h>

#define T_TOK 1024
#define NEXP 8
#define HID 1024
#define INTER 2048
#define SLOT_CAP 2176
#define NSLOT 2048
#define MAXTILES 24  // sum ceil(n_e/128) <= 23

#define BK 32
#define SPLITK 2
#define KCHUNK (INTER / SPLITK)  // 1024

typedef __bf16 bf16x8 __attribute__((ext_vector_type(8)));
typedef float f32x4 __attribute__((ext_vector_type(4)));

// async global->LDS DMA, 16B per lane; dest = wave-uniform base + lane*16
typedef const __attribute__((address_space(1))) void gv_t;
typedef __attribute__((address_space(3))) void lv_t;
static __device__ __forceinline__ void dma16(const void* g, void* l) {
  __builtin_amdgcn_global_load_lds((gv_t*)g, (lv_t*)l, 16, 0, 0);
}
#define VMW(N) asm volatile("s_waitcnt vmcnt(" #N ")" ::: "memory")
#define LKW() asm volatile("s_waitcnt lgkmcnt(0)" ::: "memory")

// ---- workspace layout (bytes) ----
#define WS_COUNTS 0
#define WS_OFFSETS 64
#define WS_TEXPERT 128
#define WS_TGATE (WS_TEXPERT + T_TOK * 2 * 4)
#define WS_TRANK (WS_TGATE + T_TOK * 2 * 4)
#define WS_TOKEN_OF (WS_TRANK + T_TOK * 2 * 4)
#define WS_GATE_OF (WS_TOKEN_OF + SLOT_CAP * 4)
#define WS_SLOT_OF (WS_GATE_OF + SLOT_CAP * 4)
#define WS_TILE_E (WS_SLOT_OF + T_TOK * 2 * 4)
#define WS_TILE_R (WS_TILE_E + 256)
#define WS_NTILES (WS_TILE_R + 256)
#define WS_ABUF 65536                           // bf16 a[SLOT_CAP][INTER]
#define WS_YS (WS_ABUF + SLOT_CAP * INTER * 2)  // fp32 ys[SPLITK][NSLOT][HID]
// xg (bf16 [SLOT_CAP][HID]) aliases the YS region: xg is consumed by gemm1
// before gemm2 writes ys, so the alias is safe and saves workspace.

// ---------------- router: softmax + top-2 ----------------
__global__ void moe_router(const float* __restrict__ logits, int* __restrict__ counts,
                           int* __restrict__ t_expert, float* __restrict__ t_gate,
                           int* __restrict__ t_rank) {
  int t = blockIdx.x * blockDim.x + threadIdx.x;
  if (t >= T_TOK) return;
  float l[NEXP];
  float mx = -1e30f;
#pragma unroll
  for (int e = 0; e < NEXP; ++e) {
    l[e] = logits[t * NEXP + e];
    mx = fmaxf(mx, l[e]);
  }
  float s = 0.f;
#pragma unroll
  for (int e = 0; e < NEXP; ++e) {
    l[e] = __expf(l[e] - mx);
    s += l[e];
  }
  float inv = 1.f / s;
  int i0 = 0;
#pragma unroll
  for (int e = 1; e < NEXP; ++e)
    if (l[e] > l[i0]) i0 = e;
  int i1 = (i0 == 0) ? 1 : 0;
#pragma unroll
  for (int e = 0; e < NEXP; ++e)
    if (e != i0 && e != i1 && l[e] > l[i1]) i1 = e;
  int es[2] = {i0, i1};
#pragma unroll
  for (int k = 0; k < 2; ++k) {
    int e = es[k];
    int r = atomicAdd(&counts[e], 1);
    int p = t * 2 + k;
    t_expert[p] = e;
    t_gate[p] = l[e] * inv;
    t_rank[p] = r;
  }
}

// ---------------- assign ----------------
__global__ void moe_assign(const int* __restrict__ counts, int* __restrict__ offsets,
                           const int* __restrict__ t_expert, const float* __restrict__ t_gate,
                           const int* __restrict__ t_rank, int* __restrict__ token_of,
                           float* __restrict__ gate_of, int* __restrict__ slot_of,
                           int* __restrict__ tile_e, int* __restrict__ tile_r,
                           int* __restrict__ n_tiles) {
  __shared__ int off_s[NEXP];
  if (threadIdx.x == 0) {
    int s = 0, nt = 0;
    for (int e = 0; e < NEXP; ++e) {
      off_s[e] = s;
      offsets[e] = s;
      int ntile = (counts[e] + 127) >> 7;
      for (int r = 0; r < ntile; ++r) {
        tile_e[nt] = e;
        tile_r[nt] = r;
        ++nt;
      }
      s += counts[e];
    }
    *n_tiles = nt;
  }
  __syncthreads();
  for (int p = threadIdx.x; p < T_TOK * 2; p += blockDim.x) {
    int e = t_expert[p];
    int slot = off_s[e] + t_rank[p];
    token_of[slot] = p >> 1;
    gate_of[slot] = t_gate[p];
    slot_of[p] = slot;
  }
}

// ---------------- xgather: xg[slot] = bf16(x[token_of[slot]]) ----------------
__global__ void moe_xgather(const float* __restrict__ x, const int* __restrict__ token_of,
                            __bf16* __restrict__ xg) {
  int idx = blockIdx.x * blockDim.x + threadIdx.x;
  int slot = idx >> 7;
  int c = (idx & 127) * 8;
  const float* src = x + (size_t)token_of[slot] * HID + c;
  float4 v0 = *(const float4*)src;
  float4 v1 = *(const float4*)(src + 4);
  bf16x8 o = {(__bf16)v0.x, (__bf16)v0.y, (__bf16)v0.z, (__bf16)v0.w,
              (__bf16)v1.x, (__bf16)v1.y, (__bf16)v1.z, (__bf16)v1.w};
  *(bf16x8*)&xg[(size_t)slot * HID + c] = o;
}

// ======================= GEMM1 =======================
// 256 threads, 4 waves (2M x 2N), BM=128, BN=64, wave tile 64x32.
// 2-stage LDS ring filled by global_load_lds DMA (no reg staging):
//   stage layout (24 KB): A bf16 [128 rows][64B]   at +0
//                         B1 fp32 [32 k][256B]      at +8192 (granule-XOR-swizzled)
//                         B3 fp32 [32 k][256B]      at +16384
// Counted vmcnt(6): consume stage t while stage t+1's 6 DMAs/wave stay in flight.
__global__ __launch_bounds__(256, 3) void moe_gemm1(
    const __bf16* __restrict__ xg, const float* __restrict__ w1, const float* __restrict__ w3,
    const int* __restrict__ offsets, const int* __restrict__ counts,
    const int* __restrict__ tile_e, const int* __restrict__ tile_r,
    const int* __restrict__ n_tiles, __bf16* __restrict__ abuf) {
  if ((int)blockIdx.y >= *n_tiles) return;
  const int e = tile_e[blockIdx.y];
  const int rt = tile_r[blockIdx.y];
  const int n_e = counts[e];
  const int off_e = offsets[e];
  const int col0 = blockIdx.x * 64;
  const int tid = threadIdx.x;
  const int lane = tid & 63;
  const int w = tid >> 6;
  const int wr = (w >> 1) * 64;
  const int wc = (w & 1) * 32;
  const int lr = lane & 15, lg = lane >> 4;

  __shared__ __align__(16) unsigned char sm[2 * 24576];

  f32x4 acc_h[4][2], acc_u[4][2];
#pragma unroll
  for (int m = 0; m < 4; ++m)
#pragma unroll
    for (int n = 0; n < 2; ++n) {
      acc_h[m][n] = (f32x4){0.f, 0.f, 0.f, 0.f};
      acc_u[m][n] = (f32x4){0.f, 0.f, 0.f, 0.f};
    }

  // ---- per-thread DMA source pointers (2 A chunks + 2 B1 + 2 B3 per wave) ----
  // A chunk c (c = w*2+j): lane covers row c*16 + (lane>>2), 16B seg (lane&3).
  const int c0 = w * 2;
  const __bf16* aSrc[2];
#pragma unroll
  for (int j = 0; j < 2; ++j) {
    int row = (c0 + j) * 16 + (lane >> 2);
    int r_loc = rt * 128 + row;
    int slot = off_e + (r_loc < n_e ? r_loc : n_e - 1);
    aSrc[j] = xg + (size_t)slot * HID + (lane & 3) * 8;
  }
  // B chunk c: lane covers k-row c*4 + (lane>>4), dest granule lane&15;
  // source granule = destg ^ ((k>>3)&3)  (XOR swizzle, applied on source).
  const float* b1Src[2];
  const float* b3Src[2];
#pragma unroll
  for (int j = 0; j < 2; ++j) {
    int kr = (c0 + j) * 4 + (lane >> 4);
    int gsrc = (lane & 15) ^ ((kr >> 3) & 3);
    size_t rowoff = (size_t)kr * INTER + col0 + gsrc * 4;
    b1Src[j] = w1 + (size_t)e * HID * INTER + rowoff;
    b3Src[j] = w3 + (size_t)e * HID * INTER + rowoff;
  }

#define G1_ISSUE(S, K0)                                                        \
  {                                                                            \
    unsigned char* base = sm + (S)*24576;                                      \
    dma16(aSrc[0] + (K0), base + (c0 + 0) * 1024);                             \
    dma16(aSrc[1] + (K0), base + (c0 + 1) * 1024);                             \
    dma16(b1Src[0] + (size_t)(K0)*INTER, base + 8192 + (c0 + 0) * 1024);       \
    dma16(b1Src[1] + (size_t)(K0)*INTER, base + 8192 + (c0 + 1) * 1024);       \
    dma16(b3Src[0] + (size_t)(K0)*INTER, base + 16384 + (c0 + 0) * 1024);      \
    dma16(b3Src[1] + (size_t)(K0)*INTER, base + 16384 + (c0 + 1) * 1024);      \
  }

  // B fragment: 8 fp32 at k=lg*8+j, col=wc+n*16+lr, swizzled granule (cg^lg)
#define G1_BFRAG(dstf, matoff, N)                                              \
  bf16x8 dstf;                                                                 \
  {                                                                            \
    int col = wc + (N)*16 + lr;                                                \
    int boff = lg * 2048 + (((col >> 2) ^ lg) << 4) + ((col & 3) << 2);        \
    const unsigned char* bb = base + (matoff) + boff;                          \
    float v0 = *(const float*)(bb + 0 * 256), v1 = *(const float*)(bb + 1 * 256); \
    float v2 = *(const float*)(bb + 2 * 256), v3 = *(const float*)(bb + 3 * 256); \
    float v4 = *(const float*)(bb + 4 * 256), v5 = *(const float*)(bb + 5 * 256); \
    float v6 = *(const float*)(bb + 6 * 256), v7 = *(const float*)(bb + 7 * 256); \
    dstf = (bf16x8){(__bf16)v0, (__bf16)v1, (__bf16)v2, (__bf16)v3,            \
                    (__bf16)v4, (__bf16)v5, (__bf16)v6, (__bf16)v7};           \
  }

  const int NT = HID / BK;  // 32
  G1_ISSUE(0, 0);
  G1_ISSUE(1, BK);
  VMW(6);
  __builtin_amdgcn_s_barrier();  // stage0 ready (stage1 in flight)

#pragma unroll 1
  for (int t = 0; t < NT; ++t) {
    const int s = t & 1;
    const unsigned char* base = sm + s * 24576;
    bf16x8 af[4];
#pragma unroll
    for (int m = 0; m < 4; ++m)
      af[m] = *(const bf16x8*)(base + (wr + m * 16 + lr) * 64 + lg * 16);
    G1_BFRAG(bf1a, 8192, 0);
    G1_BFRAG(bf1b, 8192, 1);
    G1_BFRAG(bf3a, 16384, 0);
    G1_BFRAG(bf3b, 16384, 1);
#pragma unroll
    for (int m = 0; m < 4; ++m) {
      acc_h[m][0] = __builtin_amdgcn_mfma_f32_16x16x32_bf16(af[m], bf1a, acc_h[m][0], 0, 0, 0);
      acc_h[m][1] = __builtin_amdgcn_mfma_f32_16x16x32_bf16(af[m], bf1b, acc_h[m][1], 0, 0, 0);
      acc_u[m][0] = __builtin_amdgcn_mfma_f32_16x16x32_bf16(af[m], bf3a, acc_u[m][0], 0, 0, 0);
      acc_u[m][1] = __builtin_amdgcn_mfma_f32_16x16x32_bf16(af[m], bf3b, acc_u[m][1], 0, 0, 0);
    }
    LKW();
    __builtin_amdgcn_s_barrier();  // all waves done reading stage s
    if (t + 2 < NT) {
      G1_ISSUE(s, (t + 2) * BK);  // refill stage s
      VMW(6);                     // stage t+1 done; t+2 stays in flight
    } else {
      VMW(0);
    }
    __builtin_amdgcn_s_barrier();  // stage t+1 visible to all
  }
#undef G1_ISSUE
#undef G1_BFRAG

  // epilogue: a = silu(h) * u, store bf16
#pragma unroll
  for (int m = 0; m < 4; ++m)
#pragma unroll
    for (int n = 0; n < 2; ++n) {
      int col = col0 + wc + n * 16 + lr;
#pragma unroll
      for (int r = 0; r < 4; ++r) {
        int row_loc = rt * 128 + wr + m * 16 + lg * 4 + r;
        if (row_loc < n_e) {
          float h = acc_h[m][n][r];
          float u = acc_u[m][n][r];
          float a = h / (1.f + __expf(-h)) * u;
          abuf[(size_t)(off_e + row_loc) * INTER + col] = (__bf16)a;
        }
      }
    }
}

// ======================= GEMM2 =======================
// Same DMA-ring scheme; stage (16 KB): A bf16 [128][64B] at +0, B=w2 fp32 [32][256B] at +8192.
// 4 DMAs per wave per stage -> vmcnt(4).
__global__ __launch_bounds__(256, 4) void moe_gemm2(
    const __bf16* __restrict__ abuf, const float* __restrict__ w2,
    const int* __restrict__ offsets, const int* __restrict__ counts,
    const float* __restrict__ gate_of, const int* __restrict__ tile_e,
    const int* __restrict__ tile_r, const int* __restrict__ n_tiles,
    float* __restrict__ yslot) {
  if ((int)blockIdx.y >= *n_tiles) return;
  const int e = tile_e[blockIdx.y];
  const int rt = tile_r[blockIdx.y];
  const int sk = blockIdx.z;
  const int n_e = counts[e];
  const int off_e = offsets[e];
  const int col0 = blockIdx.x * 64;
  const int kbase = sk * KCHUNK;
  const int tid = threadIdx.x;
  const int lane = tid & 63;
  const int w = tid >> 6;
  const int wr = (w >> 1) * 64;
  const int wc = (w & 1) * 32;
  const int lr = lane & 15, lg = lane >> 4;

  __shared__ __align__(16) unsigned char sm[2 * 16384];

  f32x4 acc[4][2];
#pragma unroll
  for (int m = 0; m < 4; ++m)
#pragma unroll
    for (int n = 0; n < 2; ++n) acc[m][n] = (f32x4){0.f, 0.f, 0.f, 0.f};

  const int c0 = w * 2;
  const __bf16* aSrc[2];
#pragma unroll
  for (int j = 0; j < 2; ++j) {
    int row = (c0 + j) * 16 + (lane >> 2);
    int r_loc = rt * 128 + row;
    int slot = off_e + (r_loc < n_e ? r_loc : n_e - 1);
    aSrc[j] = abuf + (size_t)slot * INTER + kbase + (lane & 3) * 8;
  }
  const float* bSrc[2];
#pragma unroll
  for (int j = 0; j < 2; ++j) {
    int kr = (c0 + j) * 4 + (lane >> 4);
    int gsrc = (lane & 15) ^ ((kr >> 3) & 3);
    bSrc[j] = w2 + (size_t)e * INTER * HID + (size_t)(kbase + kr) * HID + col0 + gsrc * 4;
  }

#define G2_ISSUE(S, K0)                                                        \
  {                                                                            \
    unsigned char* base = sm + (S)*16384;                                      \
    dma16(aSrc[0] + (K0), base + (c0 + 0) * 1024);                             \
    dma16(aSrc[1] + (K0), base + (c0 + 1) * 1024);                             \
    dma16(bSrc[0] + (size_t)(K0)*HID, base + 8192 + (c0 + 0) * 1024);          \
    dma16(bSrc[1] + (size_t)(K0)*HID, base + 8192 + (c0 + 1) * 1024);          \
  }
#define G2_BFRAG(dstf, N)                                                      \
  bf16x8 dstf;                                                                 \
  {                                                                            \
    int col = wc + (N)*16 + lr;                                                \
    int boff = lg * 2048 + (((col >> 2) ^ lg) << 4) + ((col & 3) << 2);        \
    const unsigned char* bb = base + 8192 + boff;                              \
    float v0 = *(const float*)(bb + 0 * 256), v1 = *(const float*)(bb + 1 * 256); \
    float v2 = *(const float*)(bb + 2 * 256), v3 = *(const float*)(bb + 3 * 256); \
    float v4 = *(const float*)(bb + 4 * 256), v5 = *(const float*)(bb + 5 * 256); \
    float v6 = *(const float*)(bb + 6 * 256), v7 = *(const float*)(bb + 7 * 256); \
    dstf = (bf16x8){(__bf16)v0, (__bf16)v1, (__bf16)v2, (__bf16)v3,            \
                    (__bf16)v4, (__bf16)v5, (__bf16)v6, (__bf16)v7};           \
  }

  const int NT = KCHUNK / BK;  // 32
  G2_ISSUE(0, 0);
  G2_ISSUE(1, BK);
  VMW(4);
  __builtin_amdgcn_s_barrier();

#pragma unroll 1
  for (int t = 0; t < NT; ++t) {
    const int s = t & 1;
    const unsigned char* base = sm + s * 16384;
    bf16x8 af[4];
#pragma unroll
    for (int m = 0; m < 4; ++m)
      af[m] = *(const bf16x8*)(base + (wr + m * 16 + lr) * 64 + lg * 16);
    G2_BFRAG(bfa, 0);
    G2_BFRAG(bfb, 1);
#pragma unroll
    for (int m = 0; m < 4; ++m) {
      acc[m][0] = __builtin_amdgcn_mfma_f32_16x16x32_bf16(af[m], bfa, acc[m][0], 0, 0, 0);
      acc[m][1] = __builtin_amdgcn_mfma_f32_16x16x32_bf16(af[m], bfb, acc[m][1], 0, 0, 0);
    }
    LKW();
    __builtin_amdgcn_s_barrier();
    if (t + 2 < NT) {
      G2_ISSUE(s, (t + 2) * BK);
      VMW(4);
    } else {
      VMW(0);
    }
    __builtin_amdgcn_s_barrier();
  }
#undef G2_ISSUE
#undef G2_BFRAG

  // epilogue: plain stores, each (sk,slot,col) written exactly once
  float* ysk = yslot + (size_t)sk * NSLOT * HID;
#pragma unroll
  for (int m = 0; m < 4; ++m)
#pragma unroll
    for (int n = 0; n < 2; ++n) {
      int col = col0 + wc + n * 16 + lr;
#pragma unroll
      for (int r = 0; r < 4; ++r) {
        int row_loc = rt * 128 + wr + m * 16 + lg * 4 + r;
        if (row_loc < n_e) {
          int slot = off_e + row_loc;
          ysk[(size_t)slot * HID + col] = gate_of[slot] * acc[m][n][r];
        }
      }
    }
}

// ---------------- combine ----------------
__global__ void moe_combine(const float* __restrict__ yslot, const int* __restrict__ slot_of,
                            float* __restrict__ out) {
  int i = blockIdx.x * blockDim.x + threadIdx.x;
  const int N4 = T_TOK * HID / 4;
  if (i >= N4) return;
  int t = i >> 8;
  int c4 = i & 255;
  int sA = slot_of[2 * t];
  int sB = slot_of[2 * t + 1];
  const float4* ys0 = (const float4*)yslot;
  const float4* ys1 = (const float4*)(yslot + (size_t)NSLOT * HID);
  float4 a = ys0[(size_t)sA * 256 + c4];
  float4 b = ys0[(size_t)sB * 256 + c4];
  float4 c = ys1[(size_t)sA * 256 + c4];
  float4 d = ys1[(size_t)sB * 256 + c4];
  float4 s;
  s.x = ((a.x + b.x) + c.x) + d.x;
  s.y = ((a.y + b.y) + c.y) + d.y;
  s.z = ((a.z + b.z) + c.z) + d.z;
  s.w = ((a.w + b.w) + c.w) + d.w;
  ((float4*)out)[i] = s;
}

// ---------------- launch ----------------
extern "C" void kernel_launch(void* const* d_in, const int* in_sizes, int n_in,
                              void* d_out, int out_size, void* d_ws, size_t ws_size,
                              hipStream_t stream) {
  const float* x = (const float*)d_in[0];
  const float* logits = (const float*)d_in[1];
  const float* w1 = (const float*)d_in[2];
  const float* w3 = (const float*)d_in[3];
  const float* w2 = (const float*)d_in[4];
  float* out = (float*)d_out;
  char* ws = (char*)d_ws;

  int* counts = (int*)(ws + WS_COUNTS);
  int* offsets = (int*)(ws + WS_OFFSETS);
  int* t_expert = (int*)(ws + WS_TEXPERT);
  float* t_gate = (float*)(ws + WS_TGATE);
  int* t_rank = (int*)(ws + WS_TRANK);
  int* token_of = (int*)(ws + WS_TOKEN_OF);
  float* gate_of = (float*)(ws + WS_GATE_OF);
  int* slot_of = (int*)(ws + WS_SLOT_OF);
  int* tile_e = (int*)(ws + WS_TILE_E);
  int* tile_r = (int*)(ws + WS_TILE_R);
  int* n_tiles = (int*)(ws + WS_NTILES);
  __bf16* abuf = (__bf16*)(ws + WS_ABUF);
  float* yslot = (float*)(ws + WS_YS);
  __bf16* xg = (__bf16*)(ws + WS_YS);  // alias: xg dead before gemm2 writes ys

  hipMemsetAsync(counts, 0, 64, stream);
  moe_router<<<dim3(4), dim3(256), 0, stream>>>(logits, counts, t_expert, t_gate, t_rank);
  moe_assign<<<dim3(1), dim3(256), 0, stream>>>(counts, offsets, t_expert, t_gate, t_rank,
                                                token_of, gate_of, slot_of, tile_e, tile_r,
                                                n_tiles);
  moe_xgather<<<dim3(NSLOT * (HID / 8) / 256), dim3(256), 0, stream>>>(x, token_of, xg);
  moe_gemm1<<<dim3(INTER / 64, MAXTILES), dim3(256), 0, stream>>>(
      xg, w1, w3, offsets, counts, tile_e, tile_r, n_tiles, abuf);
  moe_gemm2<<<dim3(HID / 64, MAXTILES, SPLITK), dim3(256), 0, stream>>>(
      abuf, w2, offsets, counts, gate_of, tile_e, tile_r, n_tiles, yslot);
  moe_combine<<<dim3((T_TOK * HID / 4 + 255) / 256), dim3(256), 0, stream>>>(yslot, slot_of,
                                                                             out);
}